// Round 1
// baseline (472.369 us; speedup 1.0000x reference)
//
#include <hip/hip_runtime.h>

typedef __bf16 bf16x8 __attribute__((ext_vector_type(8)));
typedef __bf16 bf16x4 __attribute__((ext_vector_type(4)));
typedef float f32x4 __attribute__((ext_vector_type(4)));

#define BH_TOT 64
#define SEQ 8192
#define DIM 64
#define NCH 16                 // n-chunks per bh in phase 1
#define CHN (SEQ / NCH)        // 512 rows per chunk
#define KV_STRIDE 68           // fp32 row stride of KV workspace (cols 0..64 used)
#define KV_ROWS 128

// ---------------------------------------------------------------------------
// Phase 1: partial KV[128][64] and Ksum[128] per (b,h), accumulated with
// fp32 atomics into d_ws. Kf = [relu(K), relu(-K)] built on the fly.
// wave w handles feature tiles {2w, 2w+1}; N-tiles: 4 of V + 1 ones-column.
// ---------------------------------------------------------------------------
__global__ __launch_bounds__(256) void fla_ph1(const float* __restrict__ K,
                                               const float* __restrict__ V,
                                               float* __restrict__ kvf) {
  const int blk = blockIdx.x;
  const int bh = blk / NCH;
  const int ch = blk % NCH;
  const float* Kp = K + (size_t)bh * SEQ * DIM + (size_t)ch * CHN * DIM;
  const float* Vp = V + (size_t)bh * SEQ * DIM + (size_t)ch * CHN * DIM;

  __shared__ __bf16 Kb[32][68];   // [n_local][dim], pad 68 to spread banks
  __shared__ __bf16 Vb[32][68];

  const int tid = threadIdx.x;
  const int lane = tid & 63;
  const int w = tid >> 6;
  const int quad = lane >> 4;
  const int col = lane & 15;

  f32x4 acc[2][5];
#pragma unroll
  for (int mt = 0; mt < 2; ++mt)
#pragma unroll
    for (int nt = 0; nt < 5; ++nt)
      acc[mt][nt] = (f32x4){0.f, 0.f, 0.f, 0.f};

  // constant B fragment for the ones-column (global col 64 of [V | 1])
  bf16x8 bones;
#pragma unroll
  for (int j = 0; j < 8; ++j) bones[j] = (__bf16)0.f;
  if (col == 0) {
#pragma unroll
    for (int j = 0; j < 8; ++j) bones[j] = (__bf16)1.0f;
  }

  const int fcol0 = ((w & 1) << 5) + col;  // K-column for this wave's features
  const bool neg = (w >= 2);               // waves 2,3: features 64..127 = relu(-K)

  for (int s = 0; s < CHN / 32; ++s) {
    const float* Ks = Kp + s * 32 * DIM;
    const float* Vs = Vp + s * 32 * DIM;
    __syncthreads();  // protect LDS from previous iteration's readers
#pragma unroll
    for (int i = 0; i < 2; ++i) {
      int idx = tid + i * 256;         // 0..511
      int r = idx >> 4;                // row 0..31
      int c4 = (idx & 15) << 2;        // col 0,4,..,60
      float4 kk = *(const float4*)(Ks + r * DIM + c4);
      float4 vv = *(const float4*)(Vs + r * DIM + c4);
      bf16x4 kb4, vb4;
      kb4[0] = (__bf16)kk.x; kb4[1] = (__bf16)kk.y;
      kb4[2] = (__bf16)kk.z; kb4[3] = (__bf16)kk.w;
      vb4[0] = (__bf16)vv.x; vb4[1] = (__bf16)vv.y;
      vb4[2] = (__bf16)vv.z; vb4[3] = (__bf16)vv.w;
      *(bf16x4*)&Kb[r][c4] = kb4;
      *(bf16x4*)&Vb[r][c4] = vb4;
    }
    __syncthreads();

    // Build fragments. A[m][k]: m = lane&15 (feature), k = quad*8+j (n_local).
    bf16x8 a0, a1, bfr[5];
#pragma unroll
    for (int j = 0; j < 8; ++j) {
      int rr = quad * 8 + j;
      float k0 = (float)Kb[rr][fcol0];
      float k1 = (float)Kb[rr][fcol0 + 16];
      if (neg) { k0 = -k0; k1 = -k1; }
      a0[j] = (__bf16)fmaxf(k0, 0.f);
      a1[j] = (__bf16)fmaxf(k1, 0.f);
      bfr[0][j] = Vb[rr][col];
      bfr[1][j] = Vb[rr][col + 16];
      bfr[2][j] = Vb[rr][col + 32];
      bfr[3][j] = Vb[rr][col + 48];
    }
    bfr[4] = bones;
#pragma unroll
    for (int nt = 0; nt < 5; ++nt) {
      acc[0][nt] = __builtin_amdgcn_mfma_f32_16x16x32_bf16(a0, bfr[nt], acc[0][nt], 0, 0, 0);
      acc[1][nt] = __builtin_amdgcn_mfma_f32_16x16x32_bf16(a1, bfr[nt], acc[1][nt], 0, 0, 0);
    }
  }

  // C/D layout: col = lane&15, row = quad*4 + reg  [measured m89/m91]
  float* dst = kvf + (size_t)bh * KV_ROWS * KV_STRIDE;
#pragma unroll
  for (int mt = 0; mt < 2; ++mt) {
    int feat = (w * 2 + mt) * 16 + quad * 4;
#pragma unroll
    for (int nt = 0; nt < 5; ++nt) {
      int c = nt * 16 + col;
      if (c <= 64) {
#pragma unroll
        for (int r = 0; r < 4; ++r)
          atomicAdd(&dst[(size_t)(feat + r) * KV_STRIDE + c], acc[mt][nt][r]);
      }
    }
  }
}

// ---------------------------------------------------------------------------
// Phase 2: out[n][m] = (Qf[n] @ KV[:,m]) / (Qf[n] @ Ksum + 1e-6)
// Each wave owns 64 rows (4 M-tiles); B fragments (5 N-tiles x 4 K-steps)
// are built once from LDS and live in registers.
// ---------------------------------------------------------------------------
__global__ __launch_bounds__(256) void fla_ph2(const float* __restrict__ Q,
                                               const float* __restrict__ kvf,
                                               float* __restrict__ out) {
  const int blk = blockIdx.x;
  const int bh = blk >> 5;
  const int rb = blk & 31;                  // 32 row-blocks of 256 rows
  const float* Qp = Q + (size_t)bh * SEQ * DIM + (size_t)rb * 256 * DIM;
  float* Op = out + (size_t)bh * SEQ * DIM + (size_t)rb * 256 * DIM;

  __shared__ __bf16 kvb[128][66];           // cols 0..63 = KV, 64 = Ksum, 65 = pad
  const float* src = kvf + (size_t)bh * KV_ROWS * KV_STRIDE;
  for (int i = threadIdx.x; i < 128 * 66; i += 256) {
    int k = i / 66;
    int c = i - k * 66;
    float v = (c <= 64) ? src[(size_t)k * KV_STRIDE + c] : 0.f;
    kvb[k][c] = (__bf16)v;
  }
  __syncthreads();

  const int lane = threadIdx.x & 63;
  const int w = threadIdx.x >> 6;
  const int quad = lane >> 4;
  const int col = lane & 15;

  // B[k][n]: k = kt*32 + quad*8 + j, n = col (+16*nt)
  bf16x8 bfr[4][5];
#pragma unroll
  for (int kt = 0; kt < 4; ++kt) {
#pragma unroll
    for (int j = 0; j < 8; ++j) {
      int k = kt * 32 + quad * 8 + j;
      bfr[kt][0][j] = kvb[k][col];
      bfr[kt][1][j] = kvb[k][col + 16];
      bfr[kt][2][j] = kvb[k][col + 32];
      bfr[kt][3][j] = kvb[k][col + 48];
      bfr[kt][4][j] = (col == 0) ? kvb[k][64] : (__bf16)0.f;
    }
  }

#pragma unroll
  for (int mt = 0; mt < 4; ++mt) {
    // A-frag loads: lane reads Q[row = base + col][quad*8 .. +7] — the wave's
    // two dwordx4 per frag tile perfectly cover 16 rows x 128B contiguous.
    const float* qrow = Qp + (size_t)(w * 64 + mt * 16 + col) * DIM;
    float4 q0 = *(const float4*)(qrow + quad * 8);
    float4 q1 = *(const float4*)(qrow + quad * 8 + 4);
    float4 q2 = *(const float4*)(qrow + 32 + quad * 8);
    float4 q3 = *(const float4*)(qrow + 32 + quad * 8 + 4);
    float qv[16];
    *(float4*)&qv[0] = q0;  *(float4*)&qv[4] = q1;
    *(float4*)&qv[8] = q2;  *(float4*)&qv[12] = q3;
    bf16x8 a0, a1, a2, a3;   // kt0: relu(q0..31) kt1: relu(q32..63) kt2/3: relu(-q)
#pragma unroll
    for (int j = 0; j < 8; ++j) {
      a0[j] = (__bf16)fmaxf(qv[j], 0.f);
      a2[j] = (__bf16)fmaxf(-qv[j], 0.f);
      a1[j] = (__bf16)fmaxf(qv[8 + j], 0.f);
      a3[j] = (__bf16)fmaxf(-qv[8 + j], 0.f);
    }
    f32x4 acc[5];
#pragma unroll
    for (int nt = 0; nt < 5; ++nt) acc[nt] = (f32x4){0.f, 0.f, 0.f, 0.f};
#pragma unroll
    for (int nt = 0; nt < 5; ++nt) {
      acc[nt] = __builtin_amdgcn_mfma_f32_16x16x32_bf16(a0, bfr[0][nt], acc[nt], 0, 0, 0);
      acc[nt] = __builtin_amdgcn_mfma_f32_16x16x32_bf16(a1, bfr[1][nt], acc[nt], 0, 0, 0);
      acc[nt] = __builtin_amdgcn_mfma_f32_16x16x32_bf16(a2, bfr[2][nt], acc[nt], 0, 0, 0);
      acc[nt] = __builtin_amdgcn_mfma_f32_16x16x32_bf16(a3, bfr[3][nt], acc[nt], 0, 0, 0);
    }
    // normalizer lives in N-tile 4, col 0 → lane (quad<<4), same reg index
    float inv[4];
#pragma unroll
    for (int r = 0; r < 4; ++r) {
      float nrm = __shfl((float)acc[4][r], lane & 48, 64);
      inv[r] = 1.0f / (nrm + 1e-6f);
    }
    float* orow = Op + (size_t)(w * 64 + mt * 16) * DIM;
#pragma unroll
    for (int nt = 0; nt < 4; ++nt)
#pragma unroll
      for (int r = 0; r < 4; ++r)
        orow[(size_t)(quad * 4 + r) * DIM + nt * 16 + col] = acc[nt][r] * inv[r];
  }
}

extern "C" void kernel_launch(void* const* d_in, const int* in_sizes, int n_in,
                              void* d_out, int out_size, void* d_ws, size_t ws_size,
                              hipStream_t stream) {
  const float* Q = (const float*)d_in[0];
  const float* K = (const float*)d_in[1];
  const float* V = (const float*)d_in[2];
  float* out = (float*)d_out;
  float* kvf = (float*)d_ws;  // 64 * 128 * 68 fp32 = 2.23 MB

  hipMemsetAsync(kvf, 0, (size_t)BH_TOT * KV_ROWS * KV_STRIDE * sizeof(float), stream);
  fla_ph1<<<dim3(BH_TOT * NCH), dim3(256), 0, stream>>>(K, V, kvf);
  fla_ph2<<<dim3(BH_TOT * 32), dim3(256), 0, stream>>>(Q, kvf, out);
}